// Round 1
// baseline (129.997 us; speedup 1.0000x reference)
//
#include <hip/hip_runtime.h>
#include <hip/hip_bf16.h>

// Problem constants (fixed by the reference setup)
#define B_     4
#define C_     256
#define H_     64
#define W_     64
#define N_     256
#define P_     7
#define S_     4
#define HW_    (H_ * W_)          // 4096
#define SPATIAL_SCALE_ 0.0625f
#define TRANS_STD_     0.1f

// -------- Pass 1: transpose (B,C,H,W) -> (B,H*W,C) so channel is contiguous --------
__global__ __launch_bounds__(256) void transpose_bchw_to_bpc(
    const float* __restrict__ in, float* __restrict__ out) {
    __shared__ float tile[32][33];
    const int b  = blockIdx.z;
    const int p0 = blockIdx.x * 32;   // spatial (y*64+x) tile base
    const int c0 = blockIdx.y * 32;   // channel tile base
    const int tx = threadIdx.x;       // 0..31
    const int ty = threadIdx.y;       // 0..7

    // coalesced read along p (innermost of BCHW)
#pragma unroll
    for (int j = 0; j < 4; ++j) {
        const int c = c0 + ty + j * 8;
        tile[ty + j * 8][tx] = in[(size_t)(b * C_ + c) * HW_ + p0 + tx];
    }
    __syncthreads();
    // coalesced write along c (innermost of BPC)
#pragma unroll
    for (int j = 0; j < 4; ++j) {
        const int p = p0 + ty + j * 8;
        out[(size_t)(b * HW_ + p) * C_ + c0 + tx] = tile[tx][ty + j * 8];
    }
}

// -------- Pass 2: one wave per (n, ph, pw) bin; lane handles 4 channels --------
__global__ __launch_bounds__(64) void deform_roi_pool_kernel(
    const float* __restrict__ tdata,   // (B, H*W, C)
    const float* __restrict__ rois,    // (N, 5)
    const float* __restrict__ offset,  // (N, 2, 7, 7)
    float* __restrict__ out) {         // (N, C, 7, 7)
    const int bin = blockIdx.x;            // n*49 + ph*7 + pw
    const int n   = bin / (P_ * P_);
    const int r   = bin - n * (P_ * P_);
    const int ph  = r / P_;
    const int pw  = r - ph * P_;
    const int c   = (threadIdx.x) * 4;     // 4 channels per lane

    // ---- per-bin scalar math (uniform across lanes) ----
    const float rb  = rois[n * 5 + 0];
    const int   b   = (int)rb;
    const float x1  = rintf(rois[n * 5 + 1]) * SPATIAL_SCALE_ - 0.5f;
    const float y1  = rintf(rois[n * 5 + 2]) * SPATIAL_SCALE_ - 0.5f;
    const float x2  = (rintf(rois[n * 5 + 3]) + 1.0f) * SPATIAL_SCALE_ - 0.5f;
    const float y2  = (rintf(rois[n * 5 + 4]) + 1.0f) * SPATIAL_SCALE_ - 0.5f;
    const float roi_w = fmaxf(x2 - x1, 0.1f);
    const float roi_h = fmaxf(y2 - y1, 0.1f);
    const float bin_w = roi_w / (float)P_;
    const float bin_h = roi_h / (float)P_;
    const float sub_w = bin_w / (float)S_;
    const float sub_h = bin_h / (float)S_;

    // part_h == ph, part_w == pw (P == PART_SIZE == 7), nc == 1
    const float trans_x = offset[((n * 2 + 0) * P_ + ph) * P_ + pw] * TRANS_STD_;
    const float trans_y = offset[((n * 2 + 1) * P_ + ph) * P_ + pw] * TRANS_STD_;

    const float wstart = (float)pw * bin_w + x1 + trans_x * roi_w;
    const float hstart = (float)ph * bin_h + y1 + trans_y * roi_h;

    const float* __restrict__ base = tdata + (size_t)b * HW_ * C_ + c;

    float4 acc = make_float4(0.f, 0.f, 0.f, 0.f);
    int count = 0;

#pragma unroll
    for (int sh = 0; sh < S_; ++sh) {
        const float h = hstart + (float)sh * sub_h;
#pragma unroll
        for (int sw = 0; sw < S_; ++sw) {
            const float w = wstart + (float)sw * sub_w;
            const bool valid = (w >= -0.5f) & (w <= (float)W_ - 0.5f) &
                               (h >= -0.5f) & (h <= (float)H_ - 0.5f);
            if (!valid) continue;
            ++count;
            const float wf = fminf(fmaxf(w, 0.0f), (float)(W_ - 1));
            const float hf = fminf(fmaxf(h, 0.0f), (float)(H_ - 1));
            const float xfl = floorf(wf);
            const float yfl = floorf(hf);
            const int x_lo = (int)xfl;
            const int x_hi = (int)ceilf(wf);
            const int y_lo = (int)yfl;
            const int y_hi = (int)ceilf(hf);
            const float dx = wf - xfl;
            const float dy = hf - yfl;
            const float w00 = (1.f - dx) * (1.f - dy);
            const float w10 = (1.f - dx) * dy;
            const float w01 = dx * (1.f - dy);
            const float w11 = dx * dy;

            const float4 d00 = *(const float4*)(base + (size_t)(y_lo * W_ + x_lo) * C_);
            const float4 d10 = *(const float4*)(base + (size_t)(y_hi * W_ + x_lo) * C_);
            const float4 d01 = *(const float4*)(base + (size_t)(y_lo * W_ + x_hi) * C_);
            const float4 d11 = *(const float4*)(base + (size_t)(y_hi * W_ + x_hi) * C_);

            acc.x += w00 * d00.x + w10 * d10.x + w01 * d01.x + w11 * d11.x;
            acc.y += w00 * d00.y + w10 * d10.y + w01 * d01.y + w11 * d11.y;
            acc.z += w00 * d00.z + w10 * d10.z + w01 * d01.z + w11 * d11.z;
            acc.w += w00 * d00.w + w10 * d10.w + w01 * d01.w + w11 * d11.w;
        }
    }

    float4 res = make_float4(0.f, 0.f, 0.f, 0.f);
    if (count > 0) {
        const float fc = (float)count;
        res.x = acc.x / fc;
        res.y = acc.y / fc;
        res.z = acc.z / fc;
        res.w = acc.w / fc;
    }

    // out[n, c+k, ph, pw], layout (N, C, 7, 7)
    const size_t obase = ((size_t)n * C_ + c) * (P_ * P_) + ph * P_ + pw;
    out[obase + 0 * (P_ * P_)] = res.x;
    out[obase + 1 * (P_ * P_)] = res.y;
    out[obase + 2 * (P_ * P_)] = res.z;
    out[obase + 3 * (P_ * P_)] = res.w;
}

extern "C" void kernel_launch(void* const* d_in, const int* in_sizes, int n_in,
                              void* d_out, int out_size, void* d_ws, size_t ws_size,
                              hipStream_t stream) {
    const float* data   = (const float*)d_in[0];
    const float* rois   = (const float*)d_in[1];
    const float* offset = (const float*)d_in[2];
    float* out   = (float*)d_out;
    float* tdata = (float*)d_ws;   // needs B*C*H*W*4 = 16 MiB

    dim3 tg(HW_ / 32, C_ / 32, B_);   // (128, 8, 4)
    dim3 tb(32, 8);
    transpose_bchw_to_bpc<<<tg, tb, 0, stream>>>(data, tdata);

    const int bins = N_ * P_ * P_;    // 12544
    deform_roi_pool_kernel<<<bins, 64, 0, stream>>>(tdata, rois, offset, out);
}

// Round 2
// 87.326 us; speedup vs baseline: 1.4886x; 1.4886x over previous
//
#include <hip/hip_runtime.h>
#include <hip/hip_bf16.h>

// Problem constants (fixed by the reference setup)
#define B_     4
#define C_     256
#define H_     64
#define W_     64
#define N_     256
#define P_     7
#define HW_    (H_ * W_)          // 4096
#define SS_    0.0625f
#define TSTD_  0.1f

// -------- Pass 1: transpose (B,C,H,W) -> (B,H*W,C), float4 both sides --------
__global__ __launch_bounds__(256) void transpose_bchw_to_bpc(
    const float* __restrict__ in, float* __restrict__ out) {
    __shared__ float tile[64][65];   // [p_local][c_local], +1 pad
    const int b  = blockIdx.z;
    const int c0 = blockIdx.y * 64;
    const int p0 = blockIdx.x * 64;
    const int tid = threadIdx.x;
    const int hi = tid >> 4;         // 0..15
    const int lo = tid & 15;         // 0..15

#pragma unroll
    for (int j = 0; j < 4; ++j) {
        const int c = hi + j * 16;   // c_local
        const float4 v = *(const float4*)&in[(size_t)(b * C_ + c0 + c) * HW_ + p0 + lo * 4];
        tile[lo * 4 + 0][c] = v.x;
        tile[lo * 4 + 1][c] = v.y;
        tile[lo * 4 + 2][c] = v.z;
        tile[lo * 4 + 3][c] = v.w;
    }
    __syncthreads();
#pragma unroll
    for (int j = 0; j < 4; ++j) {
        const int p = hi + j * 16;   // p_local
        float4 o;
        o.x = tile[p][lo * 4 + 0];
        o.y = tile[p][lo * 4 + 1];
        o.z = tile[p][lo * 4 + 2];
        o.w = tile[p][lo * 4 + 3];
        *(float4*)&out[(size_t)(b * HW_ + p0 + p) * C_ + c0 + lo * 4] = o;
    }
}

// -------- Pass 2: block = (n, quarter-of-bins); wave per bin; lane = 4 channels.
// Separable bilinear: bin sum = sum_r sum_c (rowW[r]*colW[c]) * D[r,c] over a
// <=4x4 footprint (sample span <= 1.3 px). Output staged in LDS, stored as
// contiguous runs to kill the partial-line write amplification seen in R1.
__global__ __launch_bounds__(512) void deform_roi_pool_kernel(
    const float* __restrict__ tdata,   // (B, H*W, C)
    const float* __restrict__ rois,    // (N, 5)
    const float* __restrict__ offset,  // (N, 2, 7, 7)
    float* __restrict__ out) {         // (N, C, 7, 7)
    __shared__ float lout[16 * 260];   // [bin_local(pad16)][channel(pad260)]

    const int bid  = blockIdx.x;
    const int n    = bid >> 2;
    const int q    = bid & 3;
    const int start = (q * 49) >> 2;                  // 0,12,24,36
    const int cnt   = (((q + 1) * 49) >> 2) - start;  // 12,12,12,13
    const int tid  = threadIdx.x;
    const int lane = tid & 63;
    const int wv   = tid >> 6;        // wave 0..7
    const int c4   = lane * 4;        // 4 channels per lane

    // ---- per-ROI scalars (uniform; broadcast loads) ----
    const int   b   = (int)rois[n * 5 + 0];
    const float x1  = rintf(rois[n * 5 + 1]) * SS_ - 0.5f;
    const float y1  = rintf(rois[n * 5 + 2]) * SS_ - 0.5f;
    const float x2  = (rintf(rois[n * 5 + 3]) + 1.0f) * SS_ - 0.5f;
    const float y2  = (rintf(rois[n * 5 + 4]) + 1.0f) * SS_ - 0.5f;
    const float roi_w = fmaxf(x2 - x1, 0.1f);
    const float roi_h = fmaxf(y2 - y1, 0.1f);
    const float bin_w = roi_w / 7.0f;
    const float bin_h = roi_h / 7.0f;
    const float sub_w = bin_w / 4.0f;
    const float sub_h = bin_h / 4.0f;

    const float* __restrict__ base = tdata + (size_t)b * HW_ * C_ + c4;

    for (int bl = wv; bl < cnt; bl += 8) {
        const int bin = start + bl;
        const int ph  = bin / 7;
        const int pw  = bin - ph * 7;

        const float tx = offset[(n * 2 + 0) * 49 + bin] * TSTD_;
        const float ty = offset[(n * 2 + 1) * 49 + bin] * TSTD_;
        const float wst = (float)pw * bin_w + x1 + tx * roi_w;
        const float hst = (float)ph * bin_h + y1 + ty * roi_h;

        // ---- separable weights over <=4 rows / <=4 cols (static slots) ----
        float rw0 = 0.f, rw1 = 0.f, rw2 = 0.f, rw3 = 0.f;
        float cw0 = 0.f, cw1 = 0.f, cw2 = 0.f, cw3 = 0.f;
        int ybase = -100, xbase = -100, nvh = 0, nvw = 0;
#pragma unroll
        for (int s = 0; s < 4; ++s) {
            const float h = hst + (float)s * sub_h;
            if (h >= -0.5f && h <= (float)H_ - 0.5f) {
                ++nvh;
                const float hf  = fminf(fmaxf(h, 0.f), (float)(H_ - 1));
                const float y0f = floorf(hf);
                const float dy  = hf - y0f;
                const int   y0  = (int)y0f;
                if (ybase < -50) ybase = y0;
                const int idx = y0 - ybase;            // 0..2 (span <= 1.3 px)
                rw0 += (idx == 0) ? (1.f - dy) : 0.f;
                rw1 += (idx == 1) ? (1.f - dy) : ((idx == 0) ? dy : 0.f);
                rw2 += (idx == 2) ? (1.f - dy) : ((idx == 1) ? dy : 0.f);
                rw3 += (idx == 2) ? dy : 0.f;
            }
            const float w = wst + (float)s * sub_w;
            if (w >= -0.5f && w <= (float)W_ - 0.5f) {
                ++nvw;
                const float wf  = fminf(fmaxf(w, 0.f), (float)(W_ - 1));
                const float x0f = floorf(wf);
                const float dx  = wf - x0f;
                const int   x0  = (int)x0f;
                if (xbase < -50) xbase = x0;
                const int idx = x0 - xbase;
                cw0 += (idx == 0) ? (1.f - dx) : 0.f;
                cw1 += (idx == 1) ? (1.f - dx) : ((idx == 0) ? dx : 0.f);
                cw2 += (idx == 2) ? (1.f - dx) : ((idx == 1) ? dx : 0.f);
                cw3 += (idx == 2) ? dx : 0.f;
            }
        }

        const int count = nvh * nvw;
        float4 acc = make_float4(0.f, 0.f, 0.f, 0.f);
        if (count > 0) {
            const float rws[4] = {rw0, rw1, rw2, rw3};
            const float cws[4] = {cw0, cw1, cw2, cw3};
#pragma unroll
            for (int r = 0; r < 4; ++r) {
                const float rv = rws[r];
                if (rv != 0.f) {                       // also guards row-64 OOB
                    const float* rp = base + (size_t)((ybase + r) * W_) * C_;
#pragma unroll
                    for (int cc = 0; cc < 4; ++cc) {
                        const float cv = cws[cc];
                        if (cv != 0.f) {               // also guards col-64 OOB
                            const float wgt = rv * cv;
                            const float4 d = *(const float4*)(rp + (size_t)(xbase + cc) * C_);
                            acc.x += wgt * d.x;
                            acc.y += wgt * d.y;
                            acc.z += wgt * d.z;
                            acc.w += wgt * d.w;
                        }
                    }
                }
            }
            const float fc = (float)count;
            acc.x /= fc; acc.y /= fc; acc.z /= fc; acc.w /= fc;
        }
        *(float4*)&lout[bl * 260 + c4] = acc;
    }
    __syncthreads();

    // ---- coalesced store: runs of `cnt` consecutive floats per channel ----
    const size_t obase = (size_t)n * (C_ * 49) + start;
    for (int idx = tid; idx < 256 * 16; idx += 512) {
        const int c  = idx >> 4;
        const int bl = idx & 15;
        if (bl < cnt) out[obase + (size_t)c * 49 + bl] = lout[bl * 260 + c];
    }
}

extern "C" void kernel_launch(void* const* d_in, const int* in_sizes, int n_in,
                              void* d_out, int out_size, void* d_ws, size_t ws_size,
                              hipStream_t stream) {
    const float* data   = (const float*)d_in[0];
    const float* rois   = (const float*)d_in[1];
    const float* offset = (const float*)d_in[2];
    float* out   = (float*)d_out;
    float* tdata = (float*)d_ws;   // B*C*H*W*4 = 16 MiB

    dim3 tg(HW_ / 64, C_ / 64, B_);   // (64, 4, 4)
    transpose_bchw_to_bpc<<<tg, 256, 0, stream>>>(data, tdata);

    deform_roi_pool_kernel<<<N_ * 4, 512, 0, stream>>>(tdata, rois, offset, out);
}

// Round 3
// 87.242 us; speedup vs baseline: 1.4901x; 1.0010x over previous
//
#include <hip/hip_runtime.h>
#include <hip/hip_bf16.h>

// Problem constants (fixed by the reference setup)
#define B_     4
#define C_     256
#define H_     64
#define W_     64
#define N_     256
#define P_     7
#define HW_    (H_ * W_)          // 4096
#define SS_    0.0625f
#define TSTD_  0.1f

// -------- Pass 1: transpose (B,C,H,W) -> (B,H*W,C), float4 both sides --------
__global__ __launch_bounds__(256) void transpose_bchw_to_bpc(
    const float* __restrict__ in, float* __restrict__ out) {
    __shared__ float tile[64][65];   // [p_local][c_local], +1 pad
    const int b  = blockIdx.z;
    const int c0 = blockIdx.y * 64;
    const int p0 = blockIdx.x * 64;
    const int tid = threadIdx.x;
    const int hi = tid >> 4;         // 0..15
    const int lo = tid & 15;         // 0..15

#pragma unroll
    for (int j = 0; j < 4; ++j) {
        const int c = hi + j * 16;   // c_local
        const float4 v = *(const float4*)&in[(size_t)(b * C_ + c0 + c) * HW_ + p0 + lo * 4];
        tile[lo * 4 + 0][c] = v.x;
        tile[lo * 4 + 1][c] = v.y;
        tile[lo * 4 + 2][c] = v.z;
        tile[lo * 4 + 3][c] = v.w;
    }
    __syncthreads();
#pragma unroll
    for (int j = 0; j < 4; ++j) {
        const int p = hi + j * 16;   // p_local
        float4 o;
        o.x = tile[p][lo * 4 + 0];
        o.y = tile[p][lo * 4 + 1];
        o.z = tile[p][lo * 4 + 2];
        o.w = tile[p][lo * 4 + 3];
        *(float4*)&out[(size_t)(b * HW_ + p0 + p) * C_ + c0 + lo * 4] = o;
    }
}

// -------- Pass 2: block = (n, quarter-of-bins).
// Phase A: threads 0..cnt-1 each compute ONE bin's separable bilinear weights
//          (16 cell weights, pre-divided by count) into LDS.
// Phase B: wave per bin, lane = 4 channels; pure float4 load+FMA from the
//          channel-contiguous tdata; weights broadcast from LDS.
// Phase C: coalesced store via LDS staging.
__global__ __launch_bounds__(512) void deform_roi_pool_kernel(
    const float* __restrict__ tdata,   // (B, H*W, C)
    const float* __restrict__ rois,    // (N, 5)
    const float* __restrict__ offset,  // (N, 2, 7, 7)
    float* __restrict__ out) {         // (N, C, 7, 7)
    __shared__ float lout[16 * 260];   // [bin_local][channel] (+pad)
    __shared__ float wcell[16][16];    // [bin_local][r*4+c] weights (/count folded in)
    __shared__ int   wxy[16][2];       // [bin_local][{xbase, ybase}]

    const int bid  = blockIdx.x;
    const int n    = bid >> 2;
    const int q    = bid & 3;
    const int start = (q * 49) >> 2;                  // 0,12,24,36
    const int cnt   = (((q + 1) * 49) >> 2) - start;  // 12,12,12,13
    const int tid  = threadIdx.x;
    const int lane = tid & 63;
    const int wv   = tid >> 6;        // wave 0..7
    const int c4   = lane * 4;        // 4 channels per lane

    // ---- per-ROI scalars (uniform; broadcast loads) ----
    const int   b   = (int)rois[n * 5 + 0];
    const float x1  = rintf(rois[n * 5 + 1]) * SS_ - 0.5f;
    const float y1  = rintf(rois[n * 5 + 2]) * SS_ - 0.5f;
    const float x2  = (rintf(rois[n * 5 + 3]) + 1.0f) * SS_ - 0.5f;
    const float y2  = (rintf(rois[n * 5 + 4]) + 1.0f) * SS_ - 0.5f;
    const float roi_w = fmaxf(x2 - x1, 0.1f);
    const float roi_h = fmaxf(y2 - y1, 0.1f);
    const float bin_w = roi_w / 7.0f;
    const float bin_h = roi_h / 7.0f;
    const float sub_w = bin_w / 4.0f;
    const float sub_h = bin_h / 4.0f;

    // ---- Phase A: one thread per bin computes weights ----
    if (tid < cnt) {
        const int bin = start + tid;
        const int ph  = bin / 7;
        const int pw  = bin - ph * 7;
        const float tx = offset[(n * 2 + 0) * 49 + bin] * TSTD_;
        const float ty = offset[(n * 2 + 1) * 49 + bin] * TSTD_;
        const float wst = (float)pw * bin_w + x1 + tx * roi_w;
        const float hst = (float)ph * bin_h + y1 + ty * roi_h;

        float rw0 = 0.f, rw1 = 0.f, rw2 = 0.f, rw3 = 0.f;
        float cw0 = 0.f, cw1 = 0.f, cw2 = 0.f, cw3 = 0.f;
        int ybase = -100, xbase = -100, nvh = 0, nvw = 0;
#pragma unroll
        for (int s = 0; s < 4; ++s) {
            const float h = hst + (float)s * sub_h;
            if (h >= -0.5f && h <= (float)H_ - 0.5f) {
                ++nvh;
                const float hf  = fminf(fmaxf(h, 0.f), (float)(H_ - 1));
                const float y0f = floorf(hf);
                const float dy  = hf - y0f;
                const int   y0  = (int)y0f;
                if (ybase < -50) ybase = y0;
                const int idx = y0 - ybase;            // 0..2 (span <= 1.32 px)
                rw0 += (idx == 0) ? (1.f - dy) : 0.f;
                rw1 += (idx == 1) ? (1.f - dy) : ((idx == 0) ? dy : 0.f);
                rw2 += (idx == 2) ? (1.f - dy) : ((idx == 1) ? dy : 0.f);
                rw3 += (idx == 2) ? dy : 0.f;
            }
            const float w = wst + (float)s * sub_w;
            if (w >= -0.5f && w <= (float)W_ - 0.5f) {
                ++nvw;
                const float wf  = fminf(fmaxf(w, 0.f), (float)(W_ - 1));
                const float x0f = floorf(wf);
                const float dx  = wf - x0f;
                const int   x0  = (int)x0f;
                if (xbase < -50) xbase = x0;
                const int idx = x0 - xbase;
                cw0 += (idx == 0) ? (1.f - dx) : 0.f;
                cw1 += (idx == 1) ? (1.f - dx) : ((idx == 0) ? dx : 0.f);
                cw2 += (idx == 2) ? (1.f - dx) : ((idx == 1) ? dx : 0.f);
                cw3 += (idx == 2) ? dx : 0.f;
            }
        }
        const int count = nvh * nvw;
        const float inv = (count > 0) ? (1.0f / (float)count) : 0.0f;
        if (xbase < 0) xbase = 0;
        if (ybase < 0) ybase = 0;
        wxy[tid][0] = xbase;
        wxy[tid][1] = ybase;
        wcell[tid][ 0] = rw0 * cw0 * inv;
        wcell[tid][ 1] = rw0 * cw1 * inv;
        wcell[tid][ 2] = rw0 * cw2 * inv;
        wcell[tid][ 3] = rw0 * cw3 * inv;
        wcell[tid][ 4] = rw1 * cw0 * inv;
        wcell[tid][ 5] = rw1 * cw1 * inv;
        wcell[tid][ 6] = rw1 * cw2 * inv;
        wcell[tid][ 7] = rw1 * cw3 * inv;
        wcell[tid][ 8] = rw2 * cw0 * inv;
        wcell[tid][ 9] = rw2 * cw1 * inv;
        wcell[tid][10] = rw2 * cw2 * inv;
        wcell[tid][11] = rw2 * cw3 * inv;
        wcell[tid][12] = rw3 * cw0 * inv;
        wcell[tid][13] = rw3 * cw1 * inv;
        wcell[tid][14] = rw3 * cw2 * inv;
        wcell[tid][15] = rw3 * cw3 * inv;
    }
    __syncthreads();

    // ---- Phase B: pure load+FMA per bin ----
    const float* __restrict__ base = tdata + (size_t)b * HW_ * C_ + c4;
    for (int bl = wv; bl < cnt; bl += 8) {
        const int xb = wxy[bl][0];
        const int yb = wxy[bl][1];
        const float* p = base + (size_t)(yb * W_ + xb) * C_;
        float4 acc = make_float4(0.f, 0.f, 0.f, 0.f);
#pragma unroll
        for (int r = 0; r < 4; ++r) {
#pragma unroll
            for (int cc = 0; cc < 4; ++cc) {
                const float wgt = wcell[bl][r * 4 + cc];   // LDS broadcast (uniform)
                if (wgt != 0.f) {                          // also guards OOB row/col
                    const float4 d = *(const float4*)(p + (size_t)(r * W_ + cc) * C_);
                    acc.x += wgt * d.x;
                    acc.y += wgt * d.y;
                    acc.z += wgt * d.z;
                    acc.w += wgt * d.w;
                }
            }
        }
        *(float4*)&lout[bl * 260 + c4] = acc;
    }
    __syncthreads();

    // ---- Phase C: coalesced store: runs of `cnt` consecutive floats per channel ----
    const size_t obase = (size_t)n * (C_ * 49) + start;
    for (int idx = tid; idx < 256 * 16; idx += 512) {
        const int c  = idx >> 4;
        const int bl = idx & 15;
        if (bl < cnt) out[obase + (size_t)c * 49 + bl] = lout[bl * 260 + c];
    }
}

extern "C" void kernel_launch(void* const* d_in, const int* in_sizes, int n_in,
                              void* d_out, int out_size, void* d_ws, size_t ws_size,
                              hipStream_t stream) {
    const float* data   = (const float*)d_in[0];
    const float* rois   = (const float*)d_in[1];
    const float* offset = (const float*)d_in[2];
    float* out   = (float*)d_out;
    float* tdata = (float*)d_ws;   // B*C*H*W*4 = 16 MiB

    dim3 tg(HW_ / 64, C_ / 64, B_);   // (64, 4, 4)
    transpose_bchw_to_bpc<<<tg, 256, 0, stream>>>(data, tdata);

    deform_roi_pool_kernel<<<N_ * 4, 512, 0, stream>>>(tdata, rois, offset, out);
}

// Round 4
// 82.155 us; speedup vs baseline: 1.5824x; 1.0619x over previous
//
#include <hip/hip_runtime.h>
#include <hip/hip_bf16.h>

// Problem constants (fixed by the reference setup)
#define B_     4
#define C_     256
#define H_     64
#define W_     64
#define N_     256
#define HW_    (H_ * W_)          // 4096
#define SS_    0.0625f
#define TSTD_  0.1f

// -------- Pass 1: transpose (B,C,H,W) -> (B,H*W,C), float4 both sides --------
__global__ __launch_bounds__(256) void transpose_bchw_to_bpc(
    const float* __restrict__ in, float* __restrict__ out) {
    __shared__ float tile[64][65];   // [p_local][c_local], +1 pad
    const int b  = blockIdx.z;
    const int c0 = blockIdx.y * 64;
    const int p0 = blockIdx.x * 64;
    const int tid = threadIdx.x;
    const int hi = tid >> 4;         // 0..15
    const int lo = tid & 15;         // 0..15

#pragma unroll
    for (int j = 0; j < 4; ++j) {
        const int c = hi + j * 16;   // c_local
        const float4 v = *(const float4*)&in[(size_t)(b * C_ + c0 + c) * HW_ + p0 + lo * 4];
        tile[lo * 4 + 0][c] = v.x;
        tile[lo * 4 + 1][c] = v.y;
        tile[lo * 4 + 2][c] = v.z;
        tile[lo * 4 + 3][c] = v.w;
    }
    __syncthreads();
#pragma unroll
    for (int j = 0; j < 4; ++j) {
        const int p = hi + j * 16;   // p_local
        float4 o;
        o.x = tile[p][lo * 4 + 0];
        o.y = tile[p][lo * 4 + 1];
        o.z = tile[p][lo * 4 + 2];
        o.w = tile[p][lo * 4 + 3];
        *(float4*)&out[(size_t)(b * HW_ + p0 + p) * C_ + c0 + lo * 4] = o;
    }
}

// -------- Pass 2: one block per ROI (1024 threads = 16 waves).
// Phase A: 49 threads build per-bin COMPACT lists of (elem-offset, weight/count),
//          zero-padded to a multiple of 4 (pad loads hit offset 0 -> L1-hot).
// Phase B: wave per bin (lane = 4 channels): branch-free 4-wide load+FMA loop.
// Phase C: whole-ROI (C,49) staged in LDS -> one contiguous 50KB float4 stream.
__global__ __launch_bounds__(1024) void deform_roi_pool_kernel(
    const float* __restrict__ tdata,   // (B, H*W, C)
    const float* __restrict__ rois,    // (N, 5)
    const float* __restrict__ offset,  // (N, 2, 7, 7)
    float* __restrict__ out) {         // (N, C, 7, 7)
    __shared__ float lout[49 * 260];   // [bin][channel(+pad)]  ~51KB
    __shared__ int   coff[49 * 16];    // compact cell element-offsets
    __shared__ float cwt [49 * 16];    // compact cell weights (inv-count folded)
    __shared__ int   ccnt[49];         // padded list length (multiple of 4)

    const int n    = blockIdx.x;
    const int tid  = threadIdx.x;
    const int lane = tid & 63;
    const int wv   = tid >> 6;        // wave 0..15
    const int c4   = lane * 4;        // 4 channels per lane

    const int b = (int)rois[n * 5 + 0];

    // ---- Phase A ----
    if (tid < 49) {
        const float x1  = rintf(rois[n * 5 + 1]) * SS_ - 0.5f;
        const float y1  = rintf(rois[n * 5 + 2]) * SS_ - 0.5f;
        const float x2  = (rintf(rois[n * 5 + 3]) + 1.0f) * SS_ - 0.5f;
        const float y2  = (rintf(rois[n * 5 + 4]) + 1.0f) * SS_ - 0.5f;
        const float roi_w = fmaxf(x2 - x1, 0.1f);
        const float roi_h = fmaxf(y2 - y1, 0.1f);
        const float bin_w = roi_w / 7.0f;
        const float bin_h = roi_h / 7.0f;
        const float sub_w = bin_w / 4.0f;
        const float sub_h = bin_h / 4.0f;

        const int bin = tid;
        const int ph  = bin / 7;
        const int pw  = bin - ph * 7;
        const float tx = offset[(n * 2 + 0) * 49 + bin] * TSTD_;
        const float ty = offset[(n * 2 + 1) * 49 + bin] * TSTD_;
        const float wst = (float)pw * bin_w + x1 + tx * roi_w;
        const float hst = (float)ph * bin_h + y1 + ty * roi_h;

        float rws[4] = {0.f, 0.f, 0.f, 0.f};
        float cws[4] = {0.f, 0.f, 0.f, 0.f};
        int ybase = -100, xbase = -100, nvh = 0, nvw = 0;
#pragma unroll
        for (int s = 0; s < 4; ++s) {
            const float h = hst + (float)s * sub_h;
            if (h >= -0.5f && h <= (float)H_ - 0.5f) {
                ++nvh;
                const float hf  = fminf(fmaxf(h, 0.f), (float)(H_ - 1));
                const float y0f = floorf(hf);
                const float dy  = hf - y0f;
                const int   y0  = (int)y0f;
                if (ybase < -50) ybase = y0;
                const int idx = y0 - ybase;            // 0..2 (span <= 1.3 px)
                rws[0] += (idx == 0) ? (1.f - dy) : 0.f;
                rws[1] += (idx == 1) ? (1.f - dy) : ((idx == 0) ? dy : 0.f);
                rws[2] += (idx == 2) ? (1.f - dy) : ((idx == 1) ? dy : 0.f);
                rws[3] += (idx == 2) ? dy : 0.f;
            }
            const float w = wst + (float)s * sub_w;
            if (w >= -0.5f && w <= (float)W_ - 0.5f) {
                ++nvw;
                const float wf  = fminf(fmaxf(w, 0.f), (float)(W_ - 1));
                const float x0f = floorf(wf);
                const float dx  = wf - x0f;
                const int   x0  = (int)x0f;
                if (xbase < -50) xbase = x0;
                const int idx = x0 - xbase;
                cws[0] += (idx == 0) ? (1.f - dx) : 0.f;
                cws[1] += (idx == 1) ? (1.f - dx) : ((idx == 0) ? dx : 0.f);
                cws[2] += (idx == 2) ? (1.f - dx) : ((idx == 1) ? dx : 0.f);
                cws[3] += (idx == 2) ? dx : 0.f;
            }
        }
        const int count = nvh * nvw;
        const float inv = (count > 0) ? (1.0f / (float)count) : 0.0f;
        if (xbase < 0) xbase = 0;
        if (ybase < 0) ybase = 0;

        int m = 0;
#pragma unroll
        for (int r = 0; r < 4; ++r) {
            if (rws[r] != 0.f) {
                const int rowoff = (ybase + r) * W_;
#pragma unroll
                for (int cc = 0; cc < 4; ++cc) {
                    if (cws[cc] != 0.f) {
                        coff[bin * 16 + m] = (rowoff + xbase + cc) * C_;
                        cwt [bin * 16 + m] = rws[r] * cws[cc] * inv;
                        ++m;
                    }
                }
            }
        }
        while (m & 3) { coff[bin * 16 + m] = 0; cwt[bin * 16 + m] = 0.f; ++m; }
        ccnt[bin] = m;
    }
    __syncthreads();

    // ---- Phase B: branch-free 4-wide load+FMA per bin ----
    const float* __restrict__ base = tdata + (size_t)b * HW_ * C_ + c4;
    for (int bl = wv; bl < 49; bl += 16) {
        const int m = ccnt[bl];
        float4 acc = make_float4(0.f, 0.f, 0.f, 0.f);
        for (int k = 0; k < m; k += 4) {
            const int   o0 = coff[bl * 16 + k + 0];
            const int   o1 = coff[bl * 16 + k + 1];
            const int   o2 = coff[bl * 16 + k + 2];
            const int   o3 = coff[bl * 16 + k + 3];
            const float w0 = cwt[bl * 16 + k + 0];
            const float w1 = cwt[bl * 16 + k + 1];
            const float w2 = cwt[bl * 16 + k + 2];
            const float w3 = cwt[bl * 16 + k + 3];
            const float4 d0 = *(const float4*)(base + o0);
            const float4 d1 = *(const float4*)(base + o1);
            const float4 d2 = *(const float4*)(base + o2);
            const float4 d3 = *(const float4*)(base + o3);
            acc.x += w0 * d0.x + w1 * d1.x + w2 * d2.x + w3 * d3.x;
            acc.y += w0 * d0.y + w1 * d1.y + w2 * d2.y + w3 * d3.y;
            acc.z += w0 * d0.z + w1 * d1.z + w2 * d2.z + w3 * d3.z;
            acc.w += w0 * d0.w + w1 * d1.w + w2 * d2.w + w3 * d3.w;
        }
        *(float4*)&lout[bl * 260 + c4] = acc;   // conflict-free b128 write
    }
    __syncthreads();

    // ---- Phase C: contiguous (C,49) store, float4 stream ----
    float* __restrict__ outn = out + (size_t)n * (C_ * 49);
    for (int i = tid; i < (C_ * 49) / 4; i += 1024) {
        const int e = i * 4;
        float4 o;
#pragma unroll
        for (int j = 0; j < 4; ++j) {
            const int ee = e + j;
            const int c  = ee / 49;
            const int bl = ee - c * 49;
            (&o.x)[j] = lout[bl * 260 + c];
        }
        *(float4*)(outn + e) = o;
    }
}

extern "C" void kernel_launch(void* const* d_in, const int* in_sizes, int n_in,
                              void* d_out, int out_size, void* d_ws, size_t ws_size,
                              hipStream_t stream) {
    const float* data   = (const float*)d_in[0];
    const float* rois   = (const float*)d_in[1];
    const float* offset = (const float*)d_in[2];
    float* out   = (float*)d_out;
    float* tdata = (float*)d_ws;   // B*C*H*W*4 = 16 MiB

    dim3 tg(HW_ / 64, C_ / 64, B_);   // (64, 4, 4)
    transpose_bchw_to_bpc<<<tg, 256, 0, stream>>>(data, tdata);

    deform_roi_pool_kernel<<<N_, 1024, 0, stream>>>(tdata, rois, offset, out);
}